// Round 2
// baseline (242.074 us; speedup 1.0000x reference)
//
#include <hip/hip_runtime.h>

#define HOP 256
#define SEG 1024

// y[b,i] = x[b,i] * W[pos],  W[pos] = sum_{m=0..3} aw[r+256m]*sw[r+256m]
//   where r = pos & 255, blk = pos >> 8, term m included iff
//   blk >= m && blk - m <= kmax (kmax = num_segments-1 = 8188).
//
// Grid is sized so stride (in floats) = 2 rows exactly -> pos (and the
// weight) is CONSTANT per thread across all ITER iterations. The loop is
// 8 independent load-mul-stores; loads issued up front for max MLP.

#define BLOCKS 4096
#define TPB    256
#define ITER   8   // BLOCKS*TPB*ITER == total float4 count (33,554,432 floats)

__global__ __launch_bounds__(TPB) void SegmenterTensorFlow_28698971472345_kernel(
    const float4* __restrict__ x4,
    const float* __restrict__ aw,
    const float* __restrict__ sw,
    float4* __restrict__ y4,
    int n_mask,   // N - 1
    int kmax)     // num_segments - 1
{
    const int tid = blockIdx.x * TPB + threadIdx.x;
    const int stride = BLOCKS * TPB;          // float4 stride; *4 = 2 full rows

    // Per-thread constant weight (stride*4 is a multiple of N).
    const int pos = (tid * 4) & n_mask;
    const int r   = pos & (HOP - 1);
    const int blk = pos >> 8;

    float wx = 0.f, wy = 0.f, wz = 0.f, ww = 0.f;
#pragma unroll
    for (int m = 0; m < 4; ++m) {
        if (blk >= m && (blk - m) <= kmax) {   // wave-uniform
            const float* pa = aw + r + m * HOP;
            const float* ps = sw + r + m * HOP;
            wx += pa[0] * ps[0];
            wy += pa[1] * ps[1];
            wz += pa[2] * ps[2];
            ww += pa[3] * ps[3];
        }
    }

    // Issue all ITER loads before any use -> ITER loads in flight per lane.
    float4 v[ITER];
#pragma unroll
    for (int i = 0; i < ITER; ++i)
        v[i] = x4[tid + i * stride];

#pragma unroll
    for (int i = 0; i < ITER; ++i) {
        float4 o;
        o.x = v[i].x * wx;
        o.y = v[i].y * wy;
        o.z = v[i].z * wz;
        o.w = v[i].w * ww;
        y4[tid + i * stride] = o;
    }
}

extern "C" void kernel_launch(void* const* d_in, const int* in_sizes, int n_in,
                              void* d_out, int out_size, void* d_ws, size_t ws_size,
                              hipStream_t stream) {
    const float* x  = (const float*)d_in[0];
    const float* aw = (const float*)d_in[1];
    const float* sw = (const float*)d_in[2];
    float* y = (float*)d_out;

    const int N = 1 << 21;                 // samples per row
    const int kmax = (N - SEG) / HOP;      // 8188

    SegmenterTensorFlow_28698971472345_kernel<<<dim3(BLOCKS), dim3(TPB), 0, stream>>>(
        (const float4*)x, aw, sw, (float4*)y, N - 1, kmax);
}

// Round 4
// 241.798 us; speedup vs baseline: 1.0011x; 1.0011x over previous
//
#include <hip/hip_runtime.h>

#define HOP 256
#define SEG 1024

// y[b,i] = x[b,i] * W[pos],  W[pos] = sum_{m=0..3} aw[r+256m]*sw[r+256m]
//   r = pos & 255, blk = pos >> 8; term m included iff
//   blk >= m && blk - m <= kmax  (kmax = num_segments-1 = 8188).
//
// Structure: flat one-shot copy-with-scale. One float4 per thread, 32768
// blocks x 256 threads -> 128k waves of pure TLP (the m13 copy / fill-kernel
// structure that reaches ~6.3-6.7 TB/s). Weight = 8 L1-hit loads per thread
// (windows are 4 KB, resident in L1 after first touch per CU).
// Nontemporal store: y is write-once streaming, don't thrash L2 retention.

#define TPB 256

typedef float fvec4 __attribute__((ext_vector_type(4)));  // native vector for nt builtins

__global__ __launch_bounds__(TPB) void SegmenterTensorFlow_28698971472345_kernel(
    const fvec4* __restrict__ x4,
    const float* __restrict__ aw,
    const float* __restrict__ sw,
    fvec4* __restrict__ y4,
    int n_mask,   // N - 1
    int kmax)     // num_segments - 1
{
    const int t = blockIdx.x * TPB + threadIdx.x;   // one float4 per thread

    const int pos = (t * 4) & n_mask;
    const int r   = pos & (HOP - 1);
    const int blk = pos >> 8;

    float wx = 0.f, wy = 0.f, wz = 0.f, ww = 0.f;
#pragma unroll
    for (int m = 0; m < 4; ++m) {
        if (blk >= m && (blk - m) <= kmax) {   // wave-uniform (blk same across wave)
            const float* pa = aw + r + m * HOP;
            const float* ps = sw + r + m * HOP;
            wx += pa[0] * ps[0];
            wy += pa[1] * ps[1];
            wz += pa[2] * ps[2];
            ww += pa[3] * ps[3];
        }
    }

    fvec4 v = x4[t];
    fvec4 o;
    o.x = v.x * wx;
    o.y = v.y * wy;
    o.z = v.z * wz;
    o.w = v.w * ww;
    __builtin_nontemporal_store(o, &y4[t]);
}

extern "C" void kernel_launch(void* const* d_in, const int* in_sizes, int n_in,
                              void* d_out, int out_size, void* d_ws, size_t ws_size,
                              hipStream_t stream) {
    const float* x  = (const float*)d_in[0];
    const float* aw = (const float*)d_in[1];
    const float* sw = (const float*)d_in[2];
    float* y = (float*)d_out;

    const int N = 1 << 21;                 // samples per row
    const int kmax = (N - SEG) / HOP;      // 8188
    const int total4 = out_size / 4;       // 8,388,608 float4s
    const int blocks = total4 / TPB;       // 32768

    SegmenterTensorFlow_28698971472345_kernel<<<dim3(blocks), dim3(TPB), 0, stream>>>(
        (const fvec4*)x, aw, sw, (fvec4*)y, N - 1, kmax);
}